// Round 12
// baseline (712.721 us; speedup 1.0000x reference)
//
#include <hip/hip_runtime.h>
#include <hip/hip_bf16.h>
#include <stdint.h>

#define D_MODEL 1024

typedef __attribute__((ext_vector_type(4))) float  f32x4;
typedef __attribute__((ext_vector_type(8))) __bf16 bf16x8;
typedef __attribute__((ext_vector_type(8))) unsigned short u16x8;
typedef __attribute__((ext_vector_type(4))) unsigned short u16x4;

// ---------- helpers ----------

__device__ __forceinline__ unsigned order_map(float x) {
    unsigned u = __float_as_uint(x);
    return (u & 0x80000000u) ? ~u : (u | 0x80000000u);
}
__device__ __forceinline__ float order_unmap(unsigned m) {
    unsigned b = (m & 0x80000000u) ? (m & 0x7fffffffu) : ~m;
    return __uint_as_float(b);
}
__device__ __forceinline__ unsigned short f2bf(float f) {
    unsigned u = __float_as_uint(f);
    u += 0x7fffu + ((u >> 16) & 1u);
    return (unsigned short)(u >> 16);
}

// ---------- prelude kernels (R9 set — proven) ----------

__global__ void init_u32(unsigned* __restrict__ p, int n) {
    int i = blockIdx.x * blockDim.x + threadIdx.x;
    if (i < n) p[i] = 0u;
}

__global__ void colmax_kernel(const float* __restrict__ src, int rows_per_slab,
                              int cols, unsigned* __restrict__ out_u) {
    int k = blockIdx.x * blockDim.x + threadIdx.x;
    const float* p = src + (size_t)blockIdx.y * rows_per_slab * cols + k;
    float m = -__builtin_inff();
#pragma unroll 4
    for (int r = 0; r < rows_per_slab; ++r)
        m = fmaxf(m, p[(size_t)r * cols]);
    atomicMax(&out_u[k], order_map(m));
}

#define CC_ROWS 16
__global__ __launch_bounds__(256)
void colmax_convert(const float* __restrict__ x,
                    float* __restrict__ partial,
                    unsigned short* __restrict__ xb) {
    int c4 = threadIdx.x * 4;
    size_t base = (size_t)blockIdx.x * CC_ROWS * D_MODEL + c4;
    f32x4 m4 = {-__builtin_inff(), -__builtin_inff(), -__builtin_inff(), -__builtin_inff()};
#pragma unroll 8
    for (int r = 0; r < CC_ROWS; ++r) {
        f32x4 v = *reinterpret_cast<const f32x4*>(&x[base + (size_t)r * D_MODEL]);
        u16x4 o;
#pragma unroll
        for (int e = 0; e < 4; ++e) { m4[e] = fmaxf(m4[e], v[e]); o[e] = f2bf(v[e]); }
        *reinterpret_cast<u16x4*>(&xb[base + (size_t)r * D_MODEL]) = o;
    }
    *reinterpret_cast<f32x4*>(&partial[(size_t)blockIdx.x * D_MODEL + c4]) = m4;
}

__global__ void reduce_partial(const float* __restrict__ partial,
                               unsigned* __restrict__ ma_u) {
    int col  = blockIdx.x * 256 + threadIdx.x;
    int b0   = blockIdx.y * 64;
    float m = -__builtin_inff();
#pragma unroll 8
    for (int i = 0; i < 64; ++i)
        m = fmaxf(m, partial[(size_t)(b0 + i) * D_MODEL + col]);
    atomicMax(&ma_u[col], order_map(m));
}

__global__ void scale_kernel(const unsigned* __restrict__ ma_u,
                             const unsigned* __restrict__ mw_u,
                             float* __restrict__ s) {
    int k = blockIdx.x * blockDim.x + threadIdx.x;
    if (k < D_MODEL) {
        float ma = order_unmap(ma_u[k]);
        float mw = order_unmap(mw_u[k]);
        s[k] = sqrtf(ma) / sqrtf(mw);   // ALPHA = 0.5
    }
}

__global__ void build_w_kernel(const float* __restrict__ W, const float* __restrict__ s,
                               unsigned short* __restrict__ Wp) {
    int j  = blockIdx.x;
    int k4 = threadIdx.x * 4;
    float sj = s[j];
    f32x4 w  = *reinterpret_cast<const f32x4*>(&W[(size_t)j * D_MODEL + k4]);
    f32x4 sk = *reinterpret_cast<const f32x4*>(&s[k4]);
    u16x4 o;
#pragma unroll
    for (int i = 0; i < 4; ++i) o[i] = f2bf(sj * w[i] / sk[i]);
    *reinterpret_cast<u16x4*>(&Wp[(size_t)j * D_MODEL + k4]) = o;
}

// ---------- GEMM: 256x256, 8 waves (2Mx4N), BK=32, DOUBLE buffer ----------
// R12: R9 skeleton at 64 KB LDS -> 2 blocks/CU. Per-tile vmcnt(0) drain returns
// (1-tile slack), but the co-resident block's compute covers it (m114 TLP).
// LDS-port accounting: 128 KB port traffic/block/tile x 2 blocks ~= 3100 cyc/
// tile-pair ~= R9's single-tile 3300 -> up to ~2x, port-bound.
#define GBM 256
#define GBN 256
#define GBK 32
#define GNT (D_MODEL / GBK)   // 32
#define BUF_SHORTS 8192       // 16 KB per matrix per buffer

__global__ __launch_bounds__(512, 4)
void gemm_main(const unsigned short* __restrict__ Xb,
               const unsigned short* __restrict__ Wp,
               const float* __restrict__ bias,
               float* __restrict__ out) {
    // [2 bufs A][2 bufs B], 64 KB total -> 2 blocks/CU
    __shared__ __align__(16) unsigned short lds[4 * BUF_SHORTS];

    int flat  = blockIdx.x;
    int xcd   = flat & 7;
    int j     = flat >> 3;                      // 0..63
    int col0  = (j & 3) * GBN;                  // 4 col panels
    int row0  = ((xcd << 4) + (j >> 2)) * GBM;  // within-XCD Xb reuse (R8)

    int tid  = threadIdx.x;
    int wave = tid >> 6;
    int lane = tid & 63;
    int wr   = wave >> 2;      // 0..1 : rows wr*128
    int wc   = wave & 3;       // 0..3 : cols wc*64
    int l16  = lane & 15;
    int lq   = lane >> 4;      // 0..3 : k-quarter (8 bf16)

    // staging: line = 128B = 2 rows x 32 bf16; lane l -> line (l>>3), phys slot
    // (l&7); content = logical slot (l&7)^(l>>3)  [slot=(h<<2)|q]
    int sline = lane >> 3;
    int slog  = (lane & 7) ^ sline;
    int sh    = slog >> 2;                  // row parity
    int sq    = slog & 3;                   // k-quarter

    f32x4 acc[8][4];
#pragma unroll
    for (int m = 0; m < 8; ++m)
#pragma unroll
        for (int n = 0; n < 4; ++n)
            acc[m][n] = (f32x4){0.f, 0.f, 0.f, 0.f};

    // stage tile t (A 16KB + B 16KB) into buffer b
    auto stage = [&](int t, int b) {
        int k0 = t * GBK;
#pragma unroll
        for (int r = 0; r < 2; ++r) {
            int line = r * 64 + wave * 8 + sline;     // 0..127
            const unsigned short* gA =
                Xb + (size_t)(row0 + 2 * line + sh) * D_MODEL + k0 + sq * 8;
            __builtin_amdgcn_global_load_lds(
                (const __attribute__((address_space(1))) void*)gA,
                (__attribute__((address_space(3))) void*)&lds[b * BUF_SHORTS + line * 64],
                16, 0, 0);
            const unsigned short* gB =
                Wp + (size_t)(col0 + 2 * line + sh) * D_MODEL + k0 + sq * 8;
            __builtin_amdgcn_global_load_lds(
                (const __attribute__((address_space(1))) void*)gB,
                (__attribute__((address_space(3))) void*)&lds[(2 + b) * BUF_SHORTS + line * 64],
                16, 0, 0);
        }
    };

    // prologue: tile 0
    stage(0, 0);
    asm volatile("s_waitcnt vmcnt(0)" ::: "memory");
    __builtin_amdgcn_s_barrier();

#pragma unroll 1
    for (int t = 0; t < GNT; ++t) {
        int cur = t & 1;
        bool pf = (t + 1 < GNT);
        // issue next-tile staging FIRST (lands during this tile's compute).
        // buf[cur^1] was last read at t-1; end-of-(t-1) barrier ordered it.
        if (pf) stage(t + 1, cur ^ 1);

        const char* Ab = (const char*)&lds[cur * BUF_SHORTS];
        const char* Bb = (const char*)&lds[(2 + cur) * BUF_SHORTS];

        bf16x8 bfr[4];
#pragma unroll
        for (int n = 0; n < 4; ++n) {
            int cc   = wc * 64 + n * 16 + l16;
            int line = cc >> 1;
            int o    = (((cc & 1) << 6) + (lq << 4)) ^ ((line & 7) << 4);
            bfr[n] = *reinterpret_cast<const bf16x8*>(Bb + line * 128 + o);
        }
        bf16x8 afr[8];
#pragma unroll
        for (int m = 0; m < 8; ++m) {
            int rr   = wr * 128 + m * 16 + l16;
            int line = rr >> 1;
            int o    = (((rr & 1) << 6) + (lq << 4)) ^ ((line & 7) << 4);
            afr[m] = *reinterpret_cast<const bf16x8*>(Ab + line * 128 + o);
        }

        __builtin_amdgcn_s_setprio(1);
#pragma unroll
        for (int m = 0; m < 8; ++m)
#pragma unroll
            for (int n = 0; n < 4; ++n)
                acc[m][n] = __builtin_amdgcn_mfma_f32_16x16x32_bf16(
                    afr[m], bfr[n], acc[m][n], 0, 0, 0);
        __builtin_amdgcn_s_setprio(0);

        if (pf) {
            asm volatile("s_waitcnt vmcnt(0)" ::: "memory");
            __builtin_amdgcn_s_barrier();
        }
    }

    // ---- epilogue: C/D col = lane&15, row = lq*4 + q ----
    int crow = row0 + wr * 128;
    int ccol = col0 + wc * 64;
#pragma unroll
    for (int n = 0; n < 4; ++n) {
        int col = ccol + n * 16 + l16;
        float b = bias[col];
#pragma unroll
        for (int m = 0; m < 8; ++m) {
            int r = crow + m * 16 + lq * 4;
#pragma unroll
            for (int q = 0; q < 4; ++q)
                out[(size_t)(r + q) * D_MODEL + col] = acc[m][n][q] + b;
        }
    }
}

// ---------- launch ----------

extern "C" void kernel_launch(void* const* d_in, const int* in_sizes, int n_in,
                              void* d_out, int out_size, void* d_ws, size_t ws_size,
                              hipStream_t stream) {
    const float* x    = (const float*)d_in[0];
    const float* w    = (const float*)d_in[1];
    const float* bias = (const float*)d_in[2];
    float* out        = (float*)d_out;
    const int N       = in_sizes[0] / D_MODEL;   // 32768

    // ws: [0,4K) ma_u | [4K,8K) mw_u | [8K,12K) s | [16K,16K+2M) Wp |
    //     Xb (N*D bf16) | partial (N/CC_ROWS * D f32)
    char* ws               = (char*)d_ws;
    unsigned*       ma_u   = (unsigned*)(ws);
    unsigned*       mw_u   = (unsigned*)(ws + 4096);
    float*          s      = (float*)(ws + 8192);
    unsigned short* Wp     = (unsigned short*)(ws + 16384);
    unsigned short* Xb     = (unsigned short*)(ws + 16384 + (size_t)D_MODEL * D_MODEL * 2);
    const int nPart        = N / CC_ROWS;   // 2048
    float*          part   = (float*)(ws + 16384 + (size_t)D_MODEL * D_MODEL * 2
                                               + (size_t)N * D_MODEL * 2);

    size_t need = 16384 + (size_t)D_MODEL * D_MODEL * 2 + (size_t)N * D_MODEL * 2
                + (size_t)nPart * D_MODEL * 4;
    bool preconv = ws_size >= need;

    init_u32<<<8, 256, 0, stream>>>((unsigned*)ws, 2048);

    if (preconv) {
        colmax_convert<<<nPart, 256, 0, stream>>>(x, part, Xb);
        reduce_partial<<<dim3(D_MODEL / 256, nPart / 64), 256, 0, stream>>>(part, ma_u);
    } else {
        colmax_kernel<<<dim3(D_MODEL / 256, 64), 256, 0, stream>>>(x, N / 64, D_MODEL, ma_u);
    }
    colmax_kernel<<<dim3(D_MODEL / 256, 16), 256, 0, stream>>>(w, D_MODEL / 16, D_MODEL, mw_u);
    scale_kernel<<<D_MODEL / 256, 256, 0, stream>>>(ma_u, mw_u, s);
    build_w_kernel<<<D_MODEL, 256, 0, stream>>>(w, s, Wp);

    if (preconv) {
        int nblk = (N / GBM) * (D_MODEL / GBN);   // 512
        gemm_main<<<nblk, 512, 0, stream>>>(Xb, Wp, bias, out);
    } else {
        // (prelude fallback never expected in this harness; ws is ~GB-scale)
        colmax_kernel<<<dim3(D_MODEL / 256, 64), 256, 0, stream>>>(x, N / 64, D_MODEL, ma_u);
    }
}

// Round 13
// 153.599 us; speedup vs baseline: 4.6401x; 4.6401x over previous
//
#include <hip/hip_runtime.h>
#include <hip/hip_bf16.h>
#include <stdint.h>

#define D_MODEL 1024

typedef __attribute__((ext_vector_type(4))) float  f32x4;
typedef __attribute__((ext_vector_type(8))) __bf16 bf16x8;
typedef __attribute__((ext_vector_type(8))) unsigned short u16x8;
typedef __attribute__((ext_vector_type(4))) unsigned short u16x4;

// ---------- helpers ----------

__device__ __forceinline__ unsigned short f2bf(float f) {
    unsigned u = __float_as_uint(f);
    u += 0x7fffu + ((u >> 16) & 1u);
    return (unsigned short)(u >> 16);
}

// ---------- prelude (atomic-free two-stage reductions) ----------

// column max partials of x + f32->bf16 convert. 2048 blocks (8/CU).
#define CC_ROWS 16
__global__ __launch_bounds__(256)
void colmax_convert(const float* __restrict__ x,
                    float* __restrict__ partial,
                    unsigned short* __restrict__ xb) {
    int c4 = threadIdx.x * 4;
    size_t base = (size_t)blockIdx.x * CC_ROWS * D_MODEL + c4;
    f32x4 m4 = {-__builtin_inff(), -__builtin_inff(), -__builtin_inff(), -__builtin_inff()};
#pragma unroll 8
    for (int r = 0; r < CC_ROWS; ++r) {
        f32x4 v = *reinterpret_cast<const f32x4*>(&x[base + (size_t)r * D_MODEL]);
        u16x4 o;
#pragma unroll
        for (int e = 0; e < 4; ++e) { m4[e] = fmaxf(m4[e], v[e]); o[e] = f2bf(v[e]); }
        *reinterpret_cast<u16x4*>(&xb[base + (size_t)r * D_MODEL]) = o;
    }
    *reinterpret_cast<f32x4*>(&partial[(size_t)blockIdx.x * D_MODEL + c4]) = m4;
}

// stage 2 for x: partial[2048][1024] -> partial2[32][1024]  (no atomics)
__global__ void reduce_partial(const float* __restrict__ partial,
                               float* __restrict__ partial2) {
    int col = blockIdx.x * 256 + threadIdx.x;
    int b0  = blockIdx.y * 64;
    float m = -__builtin_inff();
#pragma unroll 8
    for (int i = 0; i < 64; ++i)
        m = fmaxf(m, partial[(size_t)(b0 + i) * D_MODEL + col]);
    partial2[(size_t)blockIdx.y * D_MODEL + col] = m;
}

// w column-max partials: w[1024][1024] -> partial3[16][1024]  (no atomics)
__global__ __launch_bounds__(256)
void wcolmax_part(const float* __restrict__ w, float* __restrict__ partial3) {
    int c4 = threadIdx.x * 4;
    size_t base = (size_t)blockIdx.x * 64 * D_MODEL + c4;
    f32x4 m4 = {-__builtin_inff(), -__builtin_inff(), -__builtin_inff(), -__builtin_inff()};
#pragma unroll 8
    for (int r = 0; r < 64; ++r) {
        f32x4 v = *reinterpret_cast<const f32x4*>(&w[base + (size_t)r * D_MODEL]);
#pragma unroll
        for (int e = 0; e < 4; ++e) m4[e] = fmaxf(m4[e], v[e]);
    }
    *reinterpret_cast<f32x4*>(&partial3[(size_t)blockIdx.x * D_MODEL + c4]) = m4;
}

// final: s[k] = sqrt(max_act[k]) / sqrt(max_w[k])   (ALPHA = 0.5)
__global__ void scale2_kernel(const float* __restrict__ partial2,
                              const float* __restrict__ partial3,
                              float* __restrict__ s) {
    int k = blockIdx.x * 256 + threadIdx.x;
    float ma = -__builtin_inff();
#pragma unroll 8
    for (int i = 0; i < 32; ++i) ma = fmaxf(ma, partial2[(size_t)i * D_MODEL + k]);
    float mw = -__builtin_inff();
#pragma unroll 8
    for (int i = 0; i < 16; ++i) mw = fmaxf(mw, partial3[(size_t)i * D_MODEL + k]);
    s[k] = sqrtf(ma) / sqrtf(mw);
}

// W'[j,k] = bf16( s[j] * W[j,k] / s[k] )
__global__ void build_w_kernel(const float* __restrict__ W, const float* __restrict__ s,
                               unsigned short* __restrict__ Wp) {
    int j  = blockIdx.x;
    int k4 = threadIdx.x * 4;
    float sj = s[j];
    f32x4 w  = *reinterpret_cast<const f32x4*>(&W[(size_t)j * D_MODEL + k4]);
    f32x4 sk = *reinterpret_cast<const f32x4*>(&s[k4]);
    u16x4 o;
#pragma unroll
    for (int i = 0; i < 4; ++i) o[i] = f2bf(sj * w[i] / sk[i]);
    *reinterpret_cast<u16x4*>(&Wp[(size_t)j * D_MODEL + k4]) = o;
}

// ---------- GEMM: R9 verbatim (best measured: 88 µs) ----------
// 256x256 tile, 8 waves (2Mx4N), BK=32, TRIPLE buffer, counted vmcnt.
// stage(t+2) issued during tile t -> 2-tile slack; steady-state vmcnt(4).
// LDS: 2 rows per 128B line; slot-XOR swizzle both-sides (#21). 0 conflicts.
#define GBM 256
#define GBN 256
#define GBK 32
#define GNT (D_MODEL / GBK)   // 32
#define BUF_SHORTS 8192       // 16 KB per matrix per buffer

__global__ __launch_bounds__(512, 2)
void gemm_main(const unsigned short* __restrict__ Xb,
               const unsigned short* __restrict__ Wp,
               const float* __restrict__ bias,
               float* __restrict__ out) {
    __shared__ __align__(16) unsigned short lds[6 * BUF_SHORTS];   // 96 KB

    int flat  = blockIdx.x;
    int xcd   = flat & 7;
    int j     = flat >> 3;                      // 0..63
    int col0  = (j & 3) * GBN;                  // 4 col panels
    int row0  = ((xcd << 4) + (j >> 2)) * GBM;  // within-XCD Xb reuse (R8)

    int tid  = threadIdx.x;
    int wave = tid >> 6;
    int lane = tid & 63;
    int wr   = wave >> 2;
    int wc   = wave & 3;
    int l16  = lane & 15;
    int lq   = lane >> 4;

    int sline = lane >> 3;
    int slog  = (lane & 7) ^ sline;
    int sh    = slog >> 2;
    int sq    = slog & 3;

    f32x4 acc[8][4];
#pragma unroll
    for (int m = 0; m < 8; ++m)
#pragma unroll
        for (int n = 0; n < 4; ++n)
            acc[m][n] = (f32x4){0.f, 0.f, 0.f, 0.f};

    auto stage = [&](int t, int b) {
        int k0 = t * GBK;
#pragma unroll
        for (int r = 0; r < 2; ++r) {
            int line = r * 64 + wave * 8 + sline;
            const unsigned short* gA =
                Xb + (size_t)(row0 + 2 * line + sh) * D_MODEL + k0 + sq * 8;
            __builtin_amdgcn_global_load_lds(
                (const __attribute__((address_space(1))) void*)gA,
                (__attribute__((address_space(3))) void*)&lds[b * BUF_SHORTS + line * 64],
                16, 0, 0);
            const unsigned short* gB =
                Wp + (size_t)(col0 + 2 * line + sh) * D_MODEL + k0 + sq * 8;
            __builtin_amdgcn_global_load_lds(
                (const __attribute__((address_space(1))) void*)gB,
                (__attribute__((address_space(3))) void*)&lds[(3 + b) * BUF_SHORTS + line * 64],
                16, 0, 0);
        }
    };

    stage(0, 0);
    stage(1, 1);

    int cur = 0;
#pragma unroll 1
    for (int t = 0; t < GNT; ++t) {
        if (t + 1 < GNT) asm volatile("s_waitcnt vmcnt(4)" ::: "memory");
        else             asm volatile("s_waitcnt vmcnt(0)" ::: "memory");
        __builtin_amdgcn_s_barrier();

        if (t + 2 < GNT) {
            int bnext = cur >= 1 ? cur - 1 : cur + 2;   // (t+2)%3
            stage(t + 2, bnext);
        }

        const char* Ab = (const char*)&lds[cur * BUF_SHORTS];
        const char* Bb = (const char*)&lds[(3 + cur) * BUF_SHORTS];

        bf16x8 bfr[4];
#pragma unroll
        for (int n = 0; n < 4; ++n) {
            int cc   = wc * 64 + n * 16 + l16;
            int line = cc >> 1;
            int o    = (((cc & 1) << 6) + (lq << 4)) ^ ((line & 7) << 4);
            bfr[n] = *reinterpret_cast<const bf16x8*>(Bb + line * 128 + o);
        }
        bf16x8 afr[8];
#pragma unroll
        for (int m = 0; m < 8; ++m) {
            int rr   = wr * 128 + m * 16 + l16;
            int line = rr >> 1;
            int o    = (((rr & 1) << 6) + (lq << 4)) ^ ((line & 7) << 4);
            afr[m] = *reinterpret_cast<const bf16x8*>(Ab + line * 128 + o);
        }

        __builtin_amdgcn_s_setprio(1);
#pragma unroll
        for (int m = 0; m < 8; ++m)
#pragma unroll
            for (int n = 0; n < 4; ++n)
                acc[m][n] = __builtin_amdgcn_mfma_f32_16x16x32_bf16(
                    afr[m], bfr[n], acc[m][n], 0, 0, 0);
        __builtin_amdgcn_s_setprio(0);

        cur = cur == 2 ? 0 : cur + 1;
    }

    int crow = row0 + wr * 128;
    int ccol = col0 + wc * 64;
#pragma unroll
    for (int n = 0; n < 4; ++n) {
        int col = ccol + n * 16 + l16;
        float b = bias[col];
#pragma unroll
        for (int m = 0; m < 8; ++m) {
            int r = crow + m * 16 + lq * 4;
#pragma unroll
            for (int q = 0; q < 4; ++q)
                out[(size_t)(r + q) * D_MODEL + col] = acc[m][n][q] + b;
        }
    }
}

// ---------- launch ----------

extern "C" void kernel_launch(void* const* d_in, const int* in_sizes, int n_in,
                              void* d_out, int out_size, void* d_ws, size_t ws_size,
                              hipStream_t stream) {
    const float* x    = (const float*)d_in[0];
    const float* w    = (const float*)d_in[1];
    const float* bias = (const float*)d_in[2];
    float* out        = (float*)d_out;
    const int N       = in_sizes[0] / D_MODEL;   // 32768

    // ws: [8K,12K) s | [16K, +2M) Wp | Xb (64M) | partial (8M) | partial2 (128K)
    //     | partial3 (64K)
    char* ws               = (char*)d_ws;
    float*          s      = (float*)(ws + 8192);
    unsigned short* Wp     = (unsigned short*)(ws + 16384);
    unsigned short* Xb     = (unsigned short*)(ws + 16384 + (size_t)D_MODEL * D_MODEL * 2);
    const int nPart        = N / CC_ROWS;   // 2048
    char*  after_xb        = ws + 16384 + (size_t)D_MODEL * D_MODEL * 2
                                        + (size_t)N * D_MODEL * 2;
    float* part            = (float*)after_xb;                       // 2048 x 1024
    float* part2           = (float*)(after_xb + (size_t)nPart * D_MODEL * 4);   // 32 x 1024
    float* part3           = (float*)(after_xb + (size_t)nPart * D_MODEL * 4
                                               + (size_t)32 * D_MODEL * 4);      // 16 x 1024

    // x-chain: partials + bf16 convert, then 2-stage reduce (no atomics anywhere)
    colmax_convert<<<nPart, 256, 0, stream>>>(x, part, Xb);
    wcolmax_part<<<16, 256, 0, stream>>>(w, part3);
    reduce_partial<<<dim3(D_MODEL / 256, nPart / 64 / 32 * 32), 256, 0, stream>>>(part, part2);
    scale2_kernel<<<D_MODEL / 256, 256, 0, stream>>>(part2, part3, s);
    build_w_kernel<<<D_MODEL, 256, 0, stream>>>(w, s, Wp);

    int nblk = (N / GBM) * (D_MODEL / GBN);   // 512
    gemm_main<<<nblk, 512, 0, stream>>>(Xb, Wp, bias, out);
}

// Round 14
// 149.060 us; speedup vs baseline: 4.7814x; 1.0305x over previous
//
#include <hip/hip_runtime.h>
#include <hip/hip_bf16.h>
#include <stdint.h>

#define D_MODEL 1024

typedef __attribute__((ext_vector_type(4))) float  f32x4;
typedef __attribute__((ext_vector_type(8))) __bf16 bf16x8;
typedef __attribute__((ext_vector_type(8))) unsigned short u16x8;
typedef __attribute__((ext_vector_type(4))) unsigned short u16x4;

// ---------- helpers ----------

__device__ __forceinline__ unsigned short f2bf(float f) {
    unsigned u = __float_as_uint(f);
    u += 0x7fffu + ((u >> 16) & 1u);
    return (unsigned short)(u >> 16);
}

// ---------- prelude (4 launches total incl. GEMM; atomic-free) ----------

// blocks [0,2048): x column-max partials + f32->bf16 convert (16 rows each)
// blocks [2048,2064): w column-max partials (64 rows each)
#define CC_ROWS 16
__global__ __launch_bounds__(256)
void colmax_convert_w(const float* __restrict__ x, const float* __restrict__ w,
                      float* __restrict__ partial, float* __restrict__ partial3,
                      unsigned short* __restrict__ xb) {
    int c4 = threadIdx.x * 4;
    if (blockIdx.x < 2048) {
        size_t base = (size_t)blockIdx.x * CC_ROWS * D_MODEL + c4;
        f32x4 m4 = {-__builtin_inff(), -__builtin_inff(), -__builtin_inff(), -__builtin_inff()};
#pragma unroll 8
        for (int r = 0; r < CC_ROWS; ++r) {
            f32x4 v = *reinterpret_cast<const f32x4*>(&x[base + (size_t)r * D_MODEL]);
            u16x4 o;
#pragma unroll
            for (int e = 0; e < 4; ++e) { m4[e] = fmaxf(m4[e], v[e]); o[e] = f2bf(v[e]); }
            *reinterpret_cast<u16x4*>(&xb[base + (size_t)r * D_MODEL]) = o;
        }
        *reinterpret_cast<f32x4*>(&partial[(size_t)blockIdx.x * D_MODEL + c4]) = m4;
    } else {
        int wb = blockIdx.x - 2048;                  // 0..15
        size_t base = (size_t)wb * 64 * D_MODEL + c4;
        f32x4 m4 = {-__builtin_inff(), -__builtin_inff(), -__builtin_inff(), -__builtin_inff()};
#pragma unroll 8
        for (int r = 0; r < 64; ++r) {
            f32x4 v = *reinterpret_cast<const f32x4*>(&w[base + (size_t)r * D_MODEL]);
#pragma unroll
            for (int e = 0; e < 4; ++e) m4[e] = fmaxf(m4[e], v[e]);
        }
        *reinterpret_cast<f32x4*>(&partial3[(size_t)wb * D_MODEL + c4]) = m4;
    }
}

// partial[2048][1024] -> partial2[32][1024]  (no atomics)
__global__ void reduce_partial(const float* __restrict__ partial,
                               float* __restrict__ partial2) {
    int col = blockIdx.x * 256 + threadIdx.x;
    int b0  = blockIdx.y * 64;
    float m = -__builtin_inff();
#pragma unroll 8
    for (int i = 0; i < 64; ++i)
        m = fmaxf(m, partial[(size_t)(b0 + i) * D_MODEL + col]);
    partial2[(size_t)blockIdx.y * D_MODEL + col] = m;
}

// fused scale + build_w: each block j redundantly computes s[1024] into LDS
// (partial2 128KB + partial3 64KB, L2-resident), then emits Wp row j.
__global__ __launch_bounds__(256)
void scale_buildw(const float* __restrict__ partial2, const float* __restrict__ partial3,
                  const float* __restrict__ W, unsigned short* __restrict__ Wp) {
    __shared__ float s_lds[D_MODEL];
    int k4 = threadIdx.x * 4;
    f32x4 ma = {-__builtin_inff(), -__builtin_inff(), -__builtin_inff(), -__builtin_inff()};
#pragma unroll 8
    for (int i = 0; i < 32; ++i) {
        f32x4 v = *reinterpret_cast<const f32x4*>(&partial2[(size_t)i * D_MODEL + k4]);
#pragma unroll
        for (int e = 0; e < 4; ++e) ma[e] = fmaxf(ma[e], v[e]);
    }
    f32x4 mw = {-__builtin_inff(), -__builtin_inff(), -__builtin_inff(), -__builtin_inff()};
#pragma unroll 8
    for (int i = 0; i < 16; ++i) {
        f32x4 v = *reinterpret_cast<const f32x4*>(&partial3[(size_t)i * D_MODEL + k4]);
#pragma unroll
        for (int e = 0; e < 4; ++e) mw[e] = fmaxf(mw[e], v[e]);
    }
    f32x4 sk;
#pragma unroll
    for (int e = 0; e < 4; ++e) sk[e] = sqrtf(ma[e]) / sqrtf(mw[e]);
    *reinterpret_cast<f32x4*>(&s_lds[k4]) = sk;
    __syncthreads();

    int j  = blockIdx.x;
    float sj = s_lds[j];
    f32x4 wv = *reinterpret_cast<const f32x4*>(&W[(size_t)j * D_MODEL + k4]);
    u16x4 o;
#pragma unroll
    for (int i = 0; i < 4; ++i) o[i] = f2bf(sj * wv[i] / sk[i]);
    *reinterpret_cast<u16x4*>(&Wp[(size_t)j * D_MODEL + k4]) = o;
}

// ---------- GEMM: R13/R9 verbatim (best measured: 88 µs) ----------
// 256x256 tile, 8 waves (2Mx4N), BK=32, TRIPLE buffer, counted vmcnt.
// stage(t+2) issued during tile t -> 2-tile slack; steady-state vmcnt(4).
// LDS: 2 rows per 128B line; slot-XOR swizzle both-sides (#21). 0 conflicts.
#define GBM 256
#define GBN 256
#define GBK 32
#define GNT (D_MODEL / GBK)   // 32
#define BUF_SHORTS 8192       // 16 KB per matrix per buffer

__global__ __launch_bounds__(512, 2)
void gemm_main(const unsigned short* __restrict__ Xb,
               const unsigned short* __restrict__ Wp,
               const float* __restrict__ bias,
               float* __restrict__ out) {
    __shared__ __align__(16) unsigned short lds[6 * BUF_SHORTS];   // 96 KB

    int flat  = blockIdx.x;
    int xcd   = flat & 7;
    int j     = flat >> 3;                      // 0..63
    int col0  = (j & 3) * GBN;                  // 4 col panels
    int row0  = ((xcd << 4) + (j >> 2)) * GBM;  // within-XCD Xb reuse (R8)

    int tid  = threadIdx.x;
    int wave = tid >> 6;
    int lane = tid & 63;
    int wr   = wave >> 2;
    int wc   = wave & 3;
    int l16  = lane & 15;
    int lq   = lane >> 4;

    int sline = lane >> 3;
    int slog  = (lane & 7) ^ sline;
    int sh    = slog >> 2;
    int sq    = slog & 3;

    f32x4 acc[8][4];
#pragma unroll
    for (int m = 0; m < 8; ++m)
#pragma unroll
        for (int n = 0; n < 4; ++n)
            acc[m][n] = (f32x4){0.f, 0.f, 0.f, 0.f};

    auto stage = [&](int t, int b) {
        int k0 = t * GBK;
#pragma unroll
        for (int r = 0; r < 2; ++r) {
            int line = r * 64 + wave * 8 + sline;
            const unsigned short* gA =
                Xb + (size_t)(row0 + 2 * line + sh) * D_MODEL + k0 + sq * 8;
            __builtin_amdgcn_global_load_lds(
                (const __attribute__((address_space(1))) void*)gA,
                (__attribute__((address_space(3))) void*)&lds[b * BUF_SHORTS + line * 64],
                16, 0, 0);
            const unsigned short* gB =
                Wp + (size_t)(col0 + 2 * line + sh) * D_MODEL + k0 + sq * 8;
            __builtin_amdgcn_global_load_lds(
                (const __attribute__((address_space(1))) void*)gB,
                (__attribute__((address_space(3))) void*)&lds[(3 + b) * BUF_SHORTS + line * 64],
                16, 0, 0);
        }
    };

    stage(0, 0);
    stage(1, 1);

    int cur = 0;
#pragma unroll 1
    for (int t = 0; t < GNT; ++t) {
        if (t + 1 < GNT) asm volatile("s_waitcnt vmcnt(4)" ::: "memory");
        else             asm volatile("s_waitcnt vmcnt(0)" ::: "memory");
        __builtin_amdgcn_s_barrier();

        if (t + 2 < GNT) {
            int bnext = cur >= 1 ? cur - 1 : cur + 2;   // (t+2)%3
            stage(t + 2, bnext);
        }

        const char* Ab = (const char*)&lds[cur * BUF_SHORTS];
        const char* Bb = (const char*)&lds[(3 + cur) * BUF_SHORTS];

        bf16x8 bfr[4];
#pragma unroll
        for (int n = 0; n < 4; ++n) {
            int cc   = wc * 64 + n * 16 + l16;
            int line = cc >> 1;
            int o    = (((cc & 1) << 6) + (lq << 4)) ^ ((line & 7) << 4);
            bfr[n] = *reinterpret_cast<const bf16x8*>(Bb + line * 128 + o);
        }
        bf16x8 afr[8];
#pragma unroll
        for (int m = 0; m < 8; ++m) {
            int rr   = wr * 128 + m * 16 + l16;
            int line = rr >> 1;
            int o    = (((rr & 1) << 6) + (lq << 4)) ^ ((line & 7) << 4);
            afr[m] = *reinterpret_cast<const bf16x8*>(Ab + line * 128 + o);
        }

        __builtin_amdgcn_s_setprio(1);
#pragma unroll
        for (int m = 0; m < 8; ++m)
#pragma unroll
            for (int n = 0; n < 4; ++n)
                acc[m][n] = __builtin_amdgcn_mfma_f32_16x16x32_bf16(
                    afr[m], bfr[n], acc[m][n], 0, 0, 0);
        __builtin_amdgcn_s_setprio(0);

        cur = cur == 2 ? 0 : cur + 1;
    }

    int crow = row0 + wr * 128;
    int ccol = col0 + wc * 64;
#pragma unroll
    for (int n = 0; n < 4; ++n) {
        int col = ccol + n * 16 + l16;
        float b = bias[col];
#pragma unroll
        for (int m = 0; m < 8; ++m) {
            int r = crow + m * 16 + lq * 4;
#pragma unroll
            for (int q = 0; q < 4; ++q)
                out[(size_t)(r + q) * D_MODEL + col] = acc[m][n][q] + b;
        }
    }
}

// ---------- launch ----------

extern "C" void kernel_launch(void* const* d_in, const int* in_sizes, int n_in,
                              void* d_out, int out_size, void* d_ws, size_t ws_size,
                              hipStream_t stream) {
    const float* x    = (const float*)d_in[0];
    const float* w    = (const float*)d_in[1];
    const float* bias = (const float*)d_in[2];
    float* out        = (float*)d_out;
    const int N       = in_sizes[0] / D_MODEL;   // 32768

    // ws: [16K, +2M) Wp | Xb (64M) | partial (8M) | partial2 (128K) | partial3 (64K)
    char* ws               = (char*)d_ws;
    unsigned short* Wp     = (unsigned short*)(ws + 16384);
    unsigned short* Xb     = (unsigned short*)(ws + 16384 + (size_t)D_MODEL * D_MODEL * 2);
    const int nPart        = N / CC_ROWS;   // 2048
    char*  after_xb        = ws + 16384 + (size_t)D_MODEL * D_MODEL * 2
                                        + (size_t)N * D_MODEL * 2;
    float* part            = (float*)after_xb;                                   // 2048 x 1024
    float* part2           = (float*)(after_xb + (size_t)nPart * D_MODEL * 4);   // 32 x 1024
    float* part3           = (float*)(after_xb + (size_t)nPart * D_MODEL * 4
                                               + (size_t)32 * D_MODEL * 4);      // 16 x 1024

    // 4 launches, no atomics, no ws-init dependency
    colmax_convert_w<<<nPart + 16, 256, 0, stream>>>(x, w, part, part3, Xb);
    reduce_partial<<<dim3(D_MODEL / 256, 32), 256, 0, stream>>>(part, part2);
    scale_buildw<<<D_MODEL, 256, 0, stream>>>(part2, part3, w, Wp);

    int nblk = (N / GBM) * (D_MODEL / GBN);   // 512
    gemm_main<<<nblk, 512, 0, stream>>>(Xb, Wp, bias, out);
}